// Round 15
// baseline (1511.071 us; speedup 1.0000x reference)
//
#include <hip/hip_runtime.h>
#include <math.h>

#define EPS_S     5.9604645e-08f
#define EPS2_S    3.5527137e-15f
#define SAFMIN_S  1.1754944e-38f
#define EPS_D     1.1102230246251565e-16

// ---------- fp32 exact-op helpers (no FMA contraction) ----------
static __device__ __forceinline__ float fadd32(float a, float b){
#pragma clang fp contract(off)
    return a+b; }
static __device__ __forceinline__ float fsub32(float a, float b){
#pragma clang fp contract(off)
    return a-b; }
static __device__ __forceinline__ float fmul32(float a, float b){
#pragma clang fp contract(off)
    return a*b; }
static __device__ __forceinline__ float fdiv32(float a, float b){
#pragma clang fp contract(off)
    return a/b; }
static __device__ __forceinline__ float fsqrt32(float x){ return sqrtf(x); }

// fast f64 reciprocal: fp32 seed + 2 Newton steps (~1 ulp); value-path only
static __device__ __forceinline__ double fast_inv(double x) {
    float xf = (float)x;
    if (fabsf(xf) < 1e-35f) return 1.0 / x;
    double r = (double)(1.0f / xf);
    r = r * (2.0 - x * r);
    r = r * (2.0 - x * r);
    return r;
}

static __device__ __forceinline__ double wsum(double v) {
#pragma unroll
    for (int m = 32; m >= 1; m >>= 1) v += __shfl_xor(v, m, 64);
    return v;
}
static __device__ __forceinline__ float wmaxrf(float v) {
#pragma unroll
    for (int m = 32; m >= 1; m >>= 1) { float o = __shfl_xor(v, m, 64); v = fmaxf(v, o); }
    return v;
}
static __device__ __forceinline__ float slapy2f(float x, float y) {
    float ax = fabsf(x), ay = fabsf(y);
    float w = fmaxf(ax, ay), z = fminf(ax, ay);
    if (z == 0.0f) return w;
    float r = fdiv32(z, w);
    return fmul32(w, fsqrt32(fadd32(1.0f, fmul32(r, r))));
}
static __device__ __forceinline__ double dlapy2(double x, double y) {
    double ax = fabs(x), ay = fabs(y);
    double w = fmax(ax, ay), z = fmin(ax, ay);
    if (z == 0.0) return w;
    double r = z / w;
    return w * sqrt(1.0 + r * r);
}
static __device__ __forceinline__ float fsignf(float a, float b){ return copysignf(fabsf(a), b); }

// LAPACK >= 3.10 slartg, fp32
static __device__ __forceinline__ void slartg(float f, float g, float& cs, float& sn, float& r) {
    if (g == 0.0f)      { cs = 1.0f; sn = 0.0f; r = f; }
    else if (f == 0.0f) { cs = 0.0f; sn = copysignf(1.0f, g); r = fabsf(g); }
    else {
        float d = fsqrt32(fadd32(fmul32(f,f), fmul32(g,g)));
        cs = fdiv32(fabsf(f), d);
        r = copysignf(d, f);
        sn = fdiv32(g, r);
    }
}
static __device__ void slaev2(float a, float b, float c,
                              float& rt1, float& rt2, float& cs1, float& sn1) {
    float sm = fadd32(a,c), df = fsub32(a,c), adf = fabsf(df);
    float tb = fadd32(b,b), ab = fabsf(tb);
    float acmx, acmn;
    if (fabsf(a) > fabsf(c)) { acmx = a; acmn = c; } else { acmx = c; acmn = a; }
    float rt;
    if (adf > ab)      { float q = fdiv32(ab,adf); rt = fmul32(adf, fsqrt32(fadd32(1.0f, fmul32(q,q)))); }
    else if (adf < ab) { float q = fdiv32(adf,ab); rt = fmul32(ab,  fsqrt32(fadd32(1.0f, fmul32(q,q)))); }
    else               rt = fmul32(ab, fsqrt32(2.0f));
    int sgn1;
    if (sm < 0.0f)      { rt1 = fmul32(0.5f, fsub32(sm, rt)); sgn1 = -1;
        rt2 = fsub32(fmul32(fdiv32(acmx,rt1),acmn), fmul32(fdiv32(b,rt1),b)); }
    else if (sm > 0.0f) { rt1 = fmul32(0.5f, fadd32(sm, rt)); sgn1 = 1;
        rt2 = fsub32(fmul32(fdiv32(acmx,rt1),acmn), fmul32(fdiv32(b,rt1),b)); }
    else                { rt1 = fmul32(0.5f, rt); rt2 = fmul32(-0.5f, rt); sgn1 = 1; }
    float cs; int sgn2;
    if (df >= 0.0f) { cs = fadd32(df, rt); sgn2 = 1; } else { cs = fsub32(df, rt); sgn2 = -1; }
    float acs = fabsf(cs);
    if (acs > ab) {
        float ct = fdiv32(-tb, cs);
        sn1 = fdiv32(1.0f, fsqrt32(fadd32(1.0f, fmul32(ct,ct))));
        cs1 = fmul32(ct, sn1);
    } else {
        if (ab == 0.0f) { cs1 = 1.0f; sn1 = 0.0f; }
        else {
            float tn = fdiv32(-cs, tb);
            cs1 = fdiv32(1.0f, fsqrt32(fadd32(1.0f, fmul32(tn,tn))));
            sn1 = fmul32(tn, cs1);
        }
    }
    if (sgn1 == sgn2) { float tn = cs1; cs1 = -sn1; sn1 = tn; }
}
// DLAED5 (K==2): double internals, float outputs
static __device__ void dlaed5(int i, const float* d2f, const float* z2f, double rho,
                              float& dlt1, float& dlt2, float& dlam) {
    double d0 = d2f[0], d1 = d2f[1], z0 = z2f[0], z1 = z2f[1];
    double del = d1 - d0, a, b2, tau2, e1, e2, lam;
    if (i == 0) {
        double w = 1.0 + 2.0 * rho * (z1*z1 - z0*z0) / del;
        if (w > 0.0) {
            a = del + rho * (z0*z0 + z1*z1);
            b2 = rho * z0*z0 * del;
            tau2 = 2.0 * b2 / (a + sqrt(fabs(a*a - 4.0*b2)));
            lam = d0 + tau2; e1 = -z0 / tau2; e2 = z1 / (del - tau2);
        } else {
            a = -del + rho * (z0*z0 + z1*z1);
            b2 = rho * z1*z1 * del;
            if (a > 0.0) tau2 = -2.0*b2 / (a + sqrt(a*a + 4.0*b2));
            else         tau2 = (a - sqrt(a*a + 4.0*b2)) / 2.0;
            lam = d1 + tau2; e1 = -z0 / (del + tau2); e2 = -z1 / tau2;
        }
    } else {
        a = -del + rho * (z0*z0 + z1*z1);
        b2 = rho * z1*z1 * del;
        if (a > 0.0) tau2 = (a + sqrt(a*a + 4.0*b2)) / 2.0;
        else         tau2 = 2.0*b2 / (-a + sqrt(a*a + 4.0*b2));
        lam = d1 + tau2; e1 = -z0 / (del + tau2); e2 = -z1 / tau2;
    }
    double nrm = sqrt(e1*e1 + e2*e2);
    dlt1 = (float)(e1 / nrm); dlt2 = (float)(e2 / nrm); dlam = (float)lam;
}
// safeguarded Newton-bisection secular solver; fast_inv + 4-way unrolled accumulation
// (bracket confinement guarantees interlacing -> signs safe; values fp32-accurate)
static __device__ void secular_solve(int K, int jj, const float* dlf, const float* wvf, double rho,
                                     int& io, double& tau) {
    if (jj < K - 1) {
        double dj = dlf[jj], dj1 = dlf[jj + 1];
        double mid = 0.5 * (dj + dj1);
        double f0 = 0.0, f1 = 0.0, f2 = 0.0, f3 = 0.0;
        int i = 0;
        for (; i + 4 <= K; i += 4) {
            double w0 = wvf[i], w1 = wvf[i+1], w2 = wvf[i+2], w3 = wvf[i+3];
            f0 += w0 * w0 * fast_inv((double)dlf[i]   - mid);
            f1 += w1 * w1 * fast_inv((double)dlf[i+1] - mid);
            f2 += w2 * w2 * fast_inv((double)dlf[i+2] - mid);
            f3 += w3 * w3 * fast_inv((double)dlf[i+3] - mid);
        }
        for (; i < K; ++i) { double w = wvf[i]; f0 += w * w * fast_inv((double)dlf[i] - mid); }
        double f = 1.0 + rho * ((f0 + f1) + (f2 + f3));
        bool orgati = (f > 0.0);
        io = orgati ? jj : jj + 1;
        double dio = dlf[io];
        double lo, hi;
        if (orgati) { lo = 0.0; hi = mid - dj; }
        else        { lo = mid - dj1; hi = 0.0; }
        tau = 0.5 * (lo + hi);
        for (int it = 0; it < 30; ++it) {
            double fv0 = 0.0, fv1 = 0.0, fv2 = 0.0, fv3 = 0.0;
            double fp0 = 0.0, fp1 = 0.0, fp2 = 0.0, fp3 = 0.0;
            int q = 0;
            for (; q + 4 <= K; q += 4) {
                double i0 = fast_inv(((double)dlf[q]   - dio) - tau);
                double i1 = fast_inv(((double)dlf[q+1] - dio) - tau);
                double i2 = fast_inv(((double)dlf[q+2] - dio) - tau);
                double i3 = fast_inv(((double)dlf[q+3] - dio) - tau);
                double w0 = wvf[q], w1 = wvf[q+1], w2 = wvf[q+2], w3 = wvf[q+3];
                double r0 = w0 * w0 * i0, r1 = w1 * w1 * i1, r2 = w2 * w2 * i2, r3 = w3 * w3 * i3;
                fv0 += r0; fv1 += r1; fv2 += r2; fv3 += r3;
                fp0 += r0 * i0; fp1 += r1 * i1; fp2 += r2 * i2; fp3 += r3 * i3;
            }
            for (; q < K; ++q) {
                double iv = fast_inv(((double)dlf[q] - dio) - tau);
                double w = wvf[q];
                double r = w * w * iv;
                fv0 += r; fp0 += r * iv;
            }
            double fv = 1.0 + rho * ((fv0 + fv1) + (fv2 + fv3));
            double fp = rho * ((fp0 + fp1) + (fp2 + fp3));
            if (fv < 0.0) lo = tau; else hi = tau;
            double tn = tau - fv / fp;
            if (!(tn > lo && tn < hi)) tn = 0.5 * (lo + hi);
            double step = fabs(tn - tau);
            tau = tn;
            if (step <= 1.0e-9 * (fabs(dio) + fabs(tau))) break;
            if ((hi - lo) <= 1.0e-11 * (fabs(dio) + fabs(tau))) break;
        }
    } else {
        io = K - 1;
        double dio = dlf[io];
        double zsum = 0.0;
        for (int i = 0; i < K; ++i) { double wv = wvf[i]; zsum += wv * wv; }
        double lo = 0.0, hi = rho * zsum;
        for (int rep = 0; rep < 4; ++rep) {
            double fv = 1.0;
            for (int i = 0; i < K; ++i) {
                double wv = wvf[i];
                fv += rho * wv * wv * fast_inv(((double)dlf[i] - dio) - hi);
            }
            if (fv >= 0.0) break;
            hi *= 2.0;
        }
        tau = 0.5 * (lo + hi);
        for (int it = 0; it < 30; ++it) {
            double fv0 = 0.0, fv1 = 0.0, fv2 = 0.0, fv3 = 0.0;
            double fp0 = 0.0, fp1 = 0.0, fp2 = 0.0, fp3 = 0.0;
            int q = 0;
            for (; q + 4 <= K; q += 4) {
                double i0 = fast_inv(((double)dlf[q]   - dio) - tau);
                double i1 = fast_inv(((double)dlf[q+1] - dio) - tau);
                double i2 = fast_inv(((double)dlf[q+2] - dio) - tau);
                double i3 = fast_inv(((double)dlf[q+3] - dio) - tau);
                double w0 = wvf[q], w1 = wvf[q+1], w2 = wvf[q+2], w3 = wvf[q+3];
                double r0 = w0 * w0 * i0, r1 = w1 * w1 * i1, r2 = w2 * w2 * i2, r3 = w3 * w3 * i3;
                fv0 += r0; fv1 += r1; fv2 += r2; fv3 += r3;
                fp0 += r0 * i0; fp1 += r1 * i1; fp2 += r2 * i2; fp3 += r3 * i3;
            }
            for (; q < K; ++q) {
                double iv = fast_inv(((double)dlf[q] - dio) - tau);
                double w = wvf[q];
                double r = w * w * iv;
                fv0 += r; fp0 += r * iv;
            }
            double fv = 1.0 + rho * ((fv0 + fv1) + (fv2 + fv3));
            double fp = rho * ((fp0 + fp1) + (fp2 + fp3));
            if (fv < 0.0) lo = tau; else hi = tau;
            double tn = tau - fv / fp;
            if (!(tn > lo && tn < hi)) tn = 0.5 * (lo + hi);
            double step = fabs(tn - tau);
            tau = tn;
            if (step <= 1.0e-9 * (fabs(dio) + fabs(tau))) break;
            if ((hi - lo) <= 1.0e-11 * (fabs(dio) + fabs(tau))) break;
        }
    }
}

// ---------------- SSTEQR (compz='I'), register+shuffle state, 16x17 LDS Z-tile ----------------
static __device__ void ssteqr16_reg(float& dreg, float& ereg, float (*Zt)[17], int l) {
    const int nn = 16;
    const int nmaxit = nn * 30;
    float wcreg = 0.0f, wsreg = 0.0f;
#define D16(i) __shfl(dreg, (i), 64)
#define E16(i) __shfl(ereg, (i), 64)
    int jtot = 0, l1 = 0;
    while (l1 <= nn - 1) {
        if (l1 > 0) { if (l == l1 - 1) ereg = 0.0f; }
        int m;
        for (m = l1; m <= nn - 2; ++m) {
            float em = E16(m);
            float tst = fabsf(em);
            if (tst == 0.0f) break;
            if (tst <= fmul32(fmul32(fsqrt32(fabsf(D16(m))), fsqrt32(fabsf(D16(m+1)))), EPS_S)) {
                if (l == m) ereg = 0.0f;
                break;
            }
        }
        int lq = l1, lend = m;
        l1 = m + 1;
        if (lend == lq) continue;
        if (fabsf(D16(lend)) < fabsf(D16(lq))) { int sw = lq; lq = lend; lend = sw; }
        if (lend > lq) {
            // ---- QL ----
            for (;;) {
                int mm = lend;
                if (lq != lend) {
                    for (int q = lq; q <= lend - 1; ++q) {
                        float eq = E16(q);
                        float tst = fmul32(eq, eq);
                        if (tst <= fadd32(fmul32(fmul32(EPS2_S, fabsf(D16(q))), fabsf(D16(q+1))), SAFMIN_S)) { mm = q; break; }
                    }
                }
                if (mm < lend) { if (l == mm) ereg = 0.0f; }
                float p = D16(lq);
                if (mm == lq) { lq = lq + 1; if (lq > lend) break; continue; }
                if (mm == lq + 1) {
                    float rt1, rt2, c, s;
                    slaev2(D16(lq), E16(lq), D16(lq + 1), rt1, rt2, c, s);
                    if (l < nn) {
                        float z1 = Zt[l][lq], z2 = Zt[l][lq + 1];
                        Zt[l][lq + 1] = fsub32(fmul32(c, z2), fmul32(s, z1));
                        Zt[l][lq]     = fadd32(fmul32(s, z2), fmul32(c, z1));
                    }
                    if (l == lq)     { dreg = rt1; ereg = 0.0f; }
                    if (l == lq + 1) dreg = rt2;
                    lq += 2;
                    if (lq > lend) break;
                    continue;
                }
                if (jtot == nmaxit) break;
                jtot++;
                float g = fdiv32(fsub32(D16(lq + 1), p), fmul32(2.0f, E16(lq)));
                float r = slapy2f(g, 1.0f);
                g = fadd32(fsub32(D16(mm), p), fdiv32(E16(lq), fadd32(g, fsignf(r, g))));
                float s = 1.0f, c = 1.0f;
                p = 0.0f;
                for (int i = mm - 1; i >= lq; --i) {
                    float ei = E16(i);
                    float f = fmul32(s, ei), bq = fmul32(c, ei);
                    slartg(g, f, c, s, r);
                    if (i != mm - 1) { if (l == i + 1) ereg = r; }
                    g = fsub32(D16(i + 1), p);
                    r = fadd32(fmul32(fsub32(D16(i), g), s), fmul32(fmul32(2.0f, c), bq));
                    p = fmul32(s, r);
                    if (l == i + 1) dreg = fadd32(g, p);
                    g = fsub32(fmul32(c, r), bq);
                    if (l == i) { wcreg = c; wsreg = -s; }
                }
                for (int j = mm - 1; j >= lq; --j) {
                    float cj = __shfl(wcreg, j, 64), sj = __shfl(wsreg, j, 64);
                    if (l < nn) {
                        float z1 = Zt[l][j], z2 = Zt[l][j + 1];
                        Zt[l][j + 1] = fsub32(fmul32(cj, z2), fmul32(sj, z1));
                        Zt[l][j]     = fadd32(fmul32(sj, z2), fmul32(cj, z1));
                    }
                }
                if (l == lq) { dreg = fsub32(dreg, p); ereg = g; }
            }
        } else {
            // ---- QR ----
            for (;;) {
                int mm = lend;
                if (lq != lend) {
                    for (int q = lq; q >= lend + 1; --q) {
                        float eq1 = E16(q - 1);
                        float tst = fmul32(eq1, eq1);
                        if (tst <= fadd32(fmul32(fmul32(EPS2_S, fabsf(D16(q))), fabsf(D16(q-1))), SAFMIN_S)) { mm = q; break; }
                    }
                }
                if (mm > lend) { if (l == mm - 1) ereg = 0.0f; }
                float p = D16(lq);
                if (mm == lq) { lq = lq - 1; if (lq < lend) break; continue; }
                if (mm == lq - 1) {
                    float rt1, rt2, c, s;
                    slaev2(D16(lq - 1), E16(lq - 1), D16(lq), rt1, rt2, c, s);
                    if (l < nn) {
                        float z1 = Zt[l][lq - 1], z2 = Zt[l][lq];
                        Zt[l][lq]     = fsub32(fmul32(c, z2), fmul32(s, z1));
                        Zt[l][lq - 1] = fadd32(fmul32(s, z2), fmul32(c, z1));
                    }
                    if (l == lq - 1) { dreg = rt1; ereg = 0.0f; }
                    if (l == lq)     dreg = rt2;
                    lq -= 2;
                    if (lq < lend) break;
                    continue;
                }
                if (jtot == nmaxit) break;
                jtot++;
                float g = fdiv32(fsub32(D16(lq - 1), p), fmul32(2.0f, E16(lq - 1)));
                float r = slapy2f(g, 1.0f);
                g = fadd32(fsub32(D16(mm), p), fdiv32(E16(lq - 1), fadd32(g, fsignf(r, g))));
                float s = 1.0f, c = 1.0f;
                p = 0.0f;
                for (int i = mm; i <= lq - 1; ++i) {
                    float ei = E16(i);
                    float f = fmul32(s, ei), bq = fmul32(c, ei);
                    slartg(g, f, c, s, r);
                    if (i != mm) { if (l == i - 1) ereg = r; }
                    g = fsub32(D16(i), p);
                    r = fadd32(fmul32(fsub32(D16(i + 1), g), s), fmul32(fmul32(2.0f, c), bq));
                    p = fmul32(s, r);
                    if (l == i) dreg = fadd32(g, p);
                    g = fsub32(fmul32(c, r), bq);
                    if (l == i) { wcreg = c; wsreg = s; }
                }
                for (int j = mm; j <= lq - 1; ++j) {
                    float cj = __shfl(wcreg, j, 64), sj = __shfl(wsreg, j, 64);
                    if (l < nn) {
                        float z1 = Zt[l][j], z2 = Zt[l][j + 1];
                        Zt[l][j + 1] = fsub32(fmul32(cj, z2), fmul32(sj, z1));
                        Zt[l][j]     = fadd32(fmul32(sj, z2), fmul32(cj, z1));
                    }
                }
                if (l == lq)     dreg = fsub32(dreg, p);
                if (l == lq - 1) ereg = g;
            }
        }
    }
    // selection sort ascending + column swaps
    for (int ii = 1; ii <= nn - 1; ++ii) {
        int i = ii - 1, k = i;
        float p = D16(i);
        for (int j = ii; j <= nn - 1; ++j) { float dj = D16(j); if (dj < p) { k = j; p = dj; } }
        if (k != i) {
            float di_old = D16(i);
            if (l == k) dreg = di_old;
            if (l == i) dreg = p;
            if (l < nn) {
                float tz = Zt[l][i];
                Zt[l][i] = Zt[l][k];
                Zt[l][k] = tz;
            }
        }
    }
#undef D16
#undef E16
}

// ---------------- merge (SLAED1+2+3), templated on size; decision arithmetic preserved ----------------
template<int NM>
static __device__ void merge_dev(float (*Zm)[NM + 1], float (*Q2)[NM + 1], float (*Sm)[NM + 1],
                                 float* dd, float* zz, float* dl, float* wv, float* zt,
                                 float* bsc, int* ksh,
                                 float* rotc, float* rots, int* rotp, int* rotq,
                                 int* indxp_, int* indxq, int* indx_, int* imrg,
                                 float rho_in, int t, int nthreads) {
    const int nm = NM, n1 = NM / 2, n2 = NM - n1;
    const int row = t & 63;
    const int nw = nthreads >> 6;
    const int wq = t >> 6;
    if (t < n1)      zz[t] = Zm[n1 - 1][t];
    else if (t < nm) zz[t] = Zm[n1][t];
    __syncthreads();
    float rho = rho_in;
    if (rho < 0.0f) { if (t >= n1 && t < nm) zz[t] = -zz[t]; }
    {
        float tscal = fdiv32(1.0f, fsqrt32(2.0f));
        if (t < nm) zz[t] = fmul32(zz[t], tscal);
    }
    rho = fabsf(fmul32(2.0f, rho));
    if (t >= n1 && t < nm) indxq[t] += n1;
    __syncthreads();
    if (t < nm) dl[t] = dd[indxq[t]];
    __syncthreads();
    if (t == 0) {  // SLAMRG(n1,n2) -> imrg
        int n1sv = n1, n2sv = n2, ind1 = 0, ind2 = n1, iw = 0;
        while (n1sv > 0 && n2sv > 0) {
            if (dl[ind1] <= dl[ind2]) { imrg[iw++] = ind1++; n1sv--; }
            else                      { imrg[iw++] = ind2++; n2sv--; }
        }
        while (n1sv-- > 0) imrg[iw++] = ind1++;
        while (n2sv-- > 0) imrg[iw++] = ind2++;
    }
    __syncthreads();
    if (t < nm) indx_[t] = indxq[imrg[t]];
    __syncthreads();
    {
        float zv = (t < nm) ? fabsf(zz[t]) : 0.0f;
        float dv = (t < nm) ? fabsf(dd[t]) : 0.0f;
        float zm_w = wmaxrf(zv), dm_w = wmaxrf(dv);
        if (t == 0) { bsc[0] = zm_w; bsc[1] = dm_w; }
    }
    __syncthreads();
    float zmax = bsc[0], dmax = bsc[1];
    float tol = fmul32(4.76837158203125e-7f /* 8*2^-24 */, fmaxf(dmax, zmax));
    if (fmul32(rho, zmax) <= tol) {  // everything deflated
        if (row < nm) for (int j = wq; j < nm; j += nw) Q2[row][j] = Zm[row][indx_[j]];
        if (t == 0) for (int j = 0; j < nm; ++j) dl[j] = dd[indx_[j]];
        __syncthreads();
        if (row < nm) for (int j = wq; j < nm; j += nw) Zm[row][j] = Q2[row][j];
        if (t == 0) for (int j = 0; j < nm; ++j) { dd[j] = dl[j]; indxq[j] = j; }
        __syncthreads();
        return;
    }
    // ---- deflation scan (SLAED2): t0-serial decisions, register-carried pj state ----
    if (t == 0) {
        int k2 = nm + 1, K = 0, nrot = 0;
        int j = 0, pj = -1;
        float zpj = 0.0f, dpj = 0.0f;
        for (; j < nm; ++j) {
            int nj = indx_[j];
            if (fmul32(rho, fabsf(zz[nj])) <= tol) { k2--; indxp_[k2 - 1] = nj; }
            else { pj = nj; zpj = zz[nj]; dpj = dd[nj]; break; }
        }
        if (pj >= 0) {
            for (;;) {
                j++;
                if (j >= nm) break;
                int nj = indx_[j];
                float znj = zz[nj];
                if (fmul32(rho, fabsf(znj)) <= tol) { k2--; indxp_[k2 - 1] = nj; }
                else {
                    float sgv = zpj, cgv = znj;
                    float tg = slapy2f(cgv, sgv);
                    float dnj = dd[nj];
                    float tdf = fsub32(dnj, dpj);
                    float cg = fdiv32(cgv, tg), sg = fdiv32(-sgv, tg);
                    if (fabsf(fmul32(fmul32(tdf, cg), sg)) <= tol) {
                        zz[nj] = tg; zz[pj] = 0.0f;
                        rotc[nrot] = cg; rots[nrot] = sg; rotp[nrot] = pj; rotq[nrot] = nj; nrot++;
                        float c2 = fmul32(cg, cg), s2 = fmul32(sg, sg);
                        float tv  = fadd32(fmul32(dpj, c2), fmul32(dnj, s2));
                        float dnn = fadd32(fmul32(dpj, s2), fmul32(dnj, c2));
                        dd[nj] = dnn; dd[pj] = tv;
                        k2--;
                        int ii = 1;
                        for (;;) {
                            if (k2 + ii <= nm) {
                                if (tv < dd[indxp_[k2 + ii - 1]]) {
                                    indxp_[k2 + ii - 2] = indxp_[k2 + ii - 1];
                                    indxp_[k2 + ii - 1] = pj;
                                    ii++;
                                } else { indxp_[k2 + ii - 2] = pj; break; }
                            } else { indxp_[k2 + ii - 2] = pj; break; }
                        }
                        pj = nj; zpj = tg; dpj = dnn;
                    } else {
                        dl[K] = dpj; wv[K] = zpj; indxp_[K] = pj;
                        K++;
                        pj = nj; zpj = znj; dpj = dnj;
                    }
                }
            }
            dl[K] = dpj; wv[K] = zpj; indxp_[K] = pj;
            K++;
        }
        ksh[0] = K; ksh[1] = nrot;
    }
    __syncthreads();
    const int K = ksh[0], nrot = ksh[1];
    if (t < nm) {
        for (int q = 0; q < nrot; ++q) {
            int pjq = rotp[q], njq = rotq[q];
            float cg = rotc[q], sg = rots[q];
            float q1 = Zm[t][pjq], q2v = Zm[t][njq];
            Zm[t][pjq] = fadd32(fmul32(cg, q1), fmul32(sg, q2v));
            Zm[t][njq] = fsub32(fmul32(cg, q2v), fmul32(sg, q1));
        }
    }
    __syncthreads();
    if (row < nm) for (int j = wq; j < nm; j += nw) Q2[row][j] = Zm[row][indxp_[j]];
    if (t == 0) for (int j = K; j < nm; ++j) dl[j] = dd[indxp_[j]];
    __syncthreads();
    if (row < nm) for (int j = K + wq; j < nm; j += nw) Zm[row][j] = Q2[row][j];
    if (t == 0) for (int j = K; j < nm; ++j) dd[j] = dl[j];
    __syncthreads();
    // ---- SLAED3 ----
    if (K == 1) {
        if (t == 0) dd[0] = (float)((double)dl[0] + (double)rho * (double)wv[0] * (double)wv[0]);
        if (t < nm) Zm[t][0] = Q2[t][0];
    } else if (K == 2) {
        float v00, v10, v01, v11, r0, r1;
        dlaed5(0, dl, wv, (double)rho, v00, v10, r0);
        dlaed5(1, dl, wv, (double)rho, v01, v11, r1);
        if (t == 0) { dd[0] = r0; dd[1] = r1; }
        if (t < nm) {
            float a0 = Q2[t][0], a1 = Q2[t][1];
            Zm[t][0] = (float)((double)a0 * v00 + (double)a1 * v10);
            Zm[t][1] = (float)((double)a0 * v01 + (double)a1 * v11);
        }
    } else if (K >= 3) {
        int io = 0; double tauj = 0.0;
        if (t < K) {
            secular_solve(K, t, dl, wv, (double)rho, io, tauj);
            double dio = dl[io];
            for (int i = 0; i < K; ++i)
                Zm[i][t] = (float)(((double)dl[i] - dio) - tauj);
            dd[t] = (float)(dio + tauj);
        }
        __syncthreads();
        if (t < K) {
            // z-tilde: 4-way partial products with fast_inv (value-path reorder)
            double dlt = dl[t];
            double p0 = 1.0, p1 = 1.0, p2 = 1.0, p3 = 1.0;
            int j2 = 0;
            for (; j2 + 4 <= K; j2 += 4) {
                if (j2 != t)     p0 *= (double)Zm[t][j2]     * fast_inv(dlt - (double)dl[j2]);
                if (j2 + 1 != t) p1 *= (double)Zm[t][j2 + 1] * fast_inv(dlt - (double)dl[j2 + 1]);
                if (j2 + 2 != t) p2 *= (double)Zm[t][j2 + 2] * fast_inv(dlt - (double)dl[j2 + 2]);
                if (j2 + 3 != t) p3 *= (double)Zm[t][j2 + 3] * fast_inv(dlt - (double)dl[j2 + 3]);
            }
            for (; j2 < K; ++j2)
                if (j2 != t) p0 *= (double)Zm[t][j2] * fast_inv(dlt - (double)dl[j2]);
            double wn = (double)Zm[t][t] * ((p0 * p1) * (p2 * p3));
            zt[t] = (float)copysign(sqrt(-wn), (double)wv[t]);
        }
        __syncthreads();
        for (int j2 = 0; j2 < K; ++j2) {
            double sv = 0.0;
            if (t < K) sv = (double)zt[t] * fast_inv((double)Zm[t][j2]);
            double nr = sqrt(wsum(sv * sv));
            if (t < K) Sm[t][j2] = (float)(sv * fast_inv(nr));
        }
        __syncthreads();
        if (row < nm) {
            for (int j2 = wq; j2 < K; j2 += nw) {
                double acc = 0.0;
                for (int i = 0; i < K; ++i) acc += (double)Q2[row][i] * (double)Sm[i][j2];
                Zm[row][j2] = (float)acc;
            }
        }
    }
    __syncthreads();
    // ---- INDXQ via SLAMRG(K asc, nm-K desc) ----
    if (t == 0) {
        int n1sv = K, n2sv = nm - K, ind1 = 0, ind2 = nm - 1, iw = 0;
        while (n1sv > 0 && n2sv > 0) {
            if (dd[ind1] <= dd[ind2]) { indxq[iw++] = ind1++; n1sv--; }
            else                      { indxq[iw++] = ind2--; n2sv--; }
        }
        while (n1sv-- > 0) indxq[iw++] = ind1++;
        while (n2sv-- > 0) indxq[iw++] = ind2--;
    }
    __syncthreads();
}

// ---------------- Kernel 0: np-exact means, register-unrolled prefetch (bit-identical chain) ----------------
__global__ __launch_bounds__(64, 1)
void mean3_kernel(const float* __restrict__ x, float* __restrict__ means) {
    const int bh = blockIdx.x, b = bh >> 4, h = bh & 15, t = threadIdx.x;
    const float* xb = x + ((size_t)b * 4096) * 1024 + h * 64 + t;
    float acc = 0.0f;
    for (int s0 = 0; s0 < 4096; s0 += 64) {
        float v[64];
#pragma unroll
        for (int k = 0; k < 64; ++k) v[k] = xb[(size_t)(s0 + k) * 1024];
#pragma unroll
        for (int k = 0; k < 64; ++k) acc = fadd32(acc, v[k]);
    }
    means[bh * 64 + t] = fdiv32(acc, 4096.0f);
}

// ---------------- Kernel 1: np-exact centered Gram, double-buffered ----------------
__global__ __launch_bounds__(256, 1)
void gram_np_kernel(const float* __restrict__ x, const float* __restrict__ means,
                    float* __restrict__ gws) {
    const int t = threadIdx.x;
    const int blk = blockIdx.x;
    const int bh = blk >> 1, half = blk & 1;
    const int b = bh >> 4, h = bh & 15;
    __shared__ float xs[2][64][64];
    __shared__ float meansh[64];
    const float* xb = x + ((size_t)b * 4096) * 1024 + h * 64;
    if (t < 64) meansh[t] = means[bh * 64 + t];
    __syncthreads();

#define LOADTILE(TI, NB) do { \
    _Pragma("unroll") \
    for (int k = 0; k < 16; ++k) { \
        int e = k * 256 + t; \
        int r = e >> 6, c = e & 63; \
        xs[NB][r][c] = fsub32(xb[(size_t)((TI) * 64 + r) * 1024 + c], meansh[c]); \
    } } while (0)

    LOADTILE(0, 0);
    __syncthreads();

    const int i0 = half * 32 + (t >> 4) * 2;
    const int j0 = (t & 15) * 4;
    float a00[4], a01[4], a02[4], a03[4], a10[4], a11[4], a12[4], a13[4];
#pragma unroll
    for (int p = 0; p < 4; ++p) { a00[p]=0;a01[p]=0;a02[p]=0;a03[p]=0;a10[p]=0;a11[p]=0;a12[p]=0;a13[p]=0; }

    for (int tile = 0; tile < 64; ++tile) {
        int buf = tile & 1;
        if (tile + 1 < 64) LOADTILE(tile + 1, buf ^ 1);
        for (int r4 = 0; r4 < 16; ++r4) {
#pragma unroll
            for (int p = 0; p < 4; ++p) {
                int r = r4 * 4 + p;
                float2 xi = *(const float2*)&xs[buf][r][i0];
                float4 xj = *(const float4*)&xs[buf][r][j0];
                a00[p] = fadd32(a00[p], fmul32(xi.x, xj.x));
                a01[p] = fadd32(a01[p], fmul32(xi.x, xj.y));
                a02[p] = fadd32(a02[p], fmul32(xi.x, xj.z));
                a03[p] = fadd32(a03[p], fmul32(xi.x, xj.w));
                a10[p] = fadd32(a10[p], fmul32(xi.y, xj.x));
                a11[p] = fadd32(a11[p], fmul32(xi.y, xj.y));
                a12[p] = fadd32(a12[p], fmul32(xi.y, xj.z));
                a13[p] = fadd32(a13[p], fmul32(xi.y, xj.w));
            }
        }
        __syncthreads();
    }
#undef LOADTILE
    float* gp = gws + (size_t)bh * 4096;
    gp[(i0 + 0) * 64 + j0 + 0] = fadd32(fadd32(a00[0], a00[1]), fadd32(a00[2], a00[3]));
    gp[(i0 + 0) * 64 + j0 + 1] = fadd32(fadd32(a01[0], a01[1]), fadd32(a01[2], a01[3]));
    gp[(i0 + 0) * 64 + j0 + 2] = fadd32(fadd32(a02[0], a02[1]), fadd32(a02[2], a02[3]));
    gp[(i0 + 0) * 64 + j0 + 3] = fadd32(fadd32(a03[0], a03[1]), fadd32(a03[2], a03[3]));
    gp[(i0 + 1) * 64 + j0 + 0] = fadd32(fadd32(a10[0], a10[1]), fadd32(a10[2], a10[3]));
    gp[(i0 + 1) * 64 + j0 + 1] = fadd32(fadd32(a11[0], a11[1]), fadd32(a11[2], a11[3]));
    gp[(i0 + 1) * 64 + j0 + 2] = fadd32(fadd32(a12[0], a12[1]), fadd32(a12[2], a12[3]));
    gp[(i0 + 1) * 64 + j0 + 3] = fadd32(fadd32(a13[0], a13[1]), fadd32(a13[2], a13[3]));
}

// ---------------- Kernel 2: SSYTD2 + scale + tears -> global ----------------
__global__ __launch_bounds__(256, 1)
void tridiag_kernel(const float* __restrict__ gws, float* __restrict__ ddg,
                    float* __restrict__ eeg, float* __restrict__ tauvg,
                    float* __restrict__ vpackg, float* __restrict__ onrmg) {
    __shared__ float Am[64][65];
    __shared__ float tauv[64], dd[64], ee[64], vvv[64], www[64];
    const int t = threadIdx.x;
    const int m = blockIdx.x;
    {
        const float* gp = gws + (size_t)m * 4096;
        for (int e = t; e < 4096; e += 256) Am[e >> 6][e & 63] = gp[e];
    }
    __syncthreads();
    for (int i = 0; i <= 62; ++i) {
        double taui = 0.0;
        if (t < 64) {
            double alpha = (double)Am[i + 1][i];
            double px = (t >= i + 2) ? (double)Am[t][i] : 0.0;
            double xnorm = sqrt(wsum(px * px));
            double beta = alpha;
            if (xnorm != 0.0) {
                beta = -copysign(dlapy2(alpha, xnorm), alpha);
                taui = (beta - alpha) / beta;
                double rs = 1.0 / (alpha - beta);
                if (t >= i + 2) Am[t][i] = (float)((double)Am[t][i] * rs);
            }
            if (t == 0) { ee[i] = (float)beta; tauv[i] = (float)taui; }
        }
        __syncthreads();
        float taub = tauv[i];
        if (taub != 0.0f) {
            if (t < 64 && t >= i + 1) vvv[t] = (t == i + 1) ? 1.0f : Am[t][i];
            __syncthreads();
            if (t < 64) {
                double wr = 0.0;
                if (t >= i + 1) {
                    for (int c = i + 1; c < 64; ++c) wr += (double)Am[t][c] * (double)vvv[c];
                    wr *= taui;
                }
                double dotwv = wsum((t >= i + 1) ? wr * (double)vvv[t] : 0.0);
                double alp2 = -0.5 * taui * dotwv;
                if (t >= i + 1) www[t] = (float)(wr + alp2 * (double)vvv[t]);
            }
            __syncthreads();
            {   // rank-2 update parallel over all 256 threads (elementwise, bit-identical)
                int r = t & 63, w4 = t >> 6;
                if (r >= i + 1) {
                    double vt = vvv[r], wt = www[r];
                    for (int c = i + 1 + w4; c < 64; c += 4)
                        Am[r][c] = (float)((double)Am[r][c] - vt * (double)www[c] - wt * (double)vvv[c]);
                }
            }
            __syncthreads();
        } else {
            __syncthreads();
        }
        if (t == 0) dd[i] = Am[i][i];
    }
    if (t == 0) dd[63] = Am[63][63];
    __syncthreads();
    if (t < 64) {   // pack reflectors direct to global
        int off = 0;
        for (int i = 0; i <= 61; ++i) {
            if (t >= i + 2) vpackg[(size_t)m * 1953 + off + t - (i + 2)] = Am[t][i];
            off += 62 - i;
        }
    }
    if (t < 64) {   // scale
        float onval = fmaxf(fabsf(dd[t]), (t < 63) ? fabsf(ee[t]) : 0.0f);
        float onrm = wmaxrf(onval);
        float mul = fdiv32(1.0f, onrm);
        dd[t] = fmul32(dd[t], mul);
        if (t < 63) ee[t] = fmul32(ee[t], mul);
        if (t == 0) onrmg[m] = onrm;
    }
    __syncthreads();
    if (t == 0) {   // rank-one tears
        int bnds[3] = {15, 31, 47};
        for (int q = 0; q < 3; ++q) {
            int bd = bnds[q];
            float ab = fabsf(ee[bd]);
            dd[bd]     = fsub32(dd[bd], ab);
            dd[bd + 1] = fsub32(dd[bd + 1], ab);
        }
    }
    __syncthreads();
    if (t < 64) {
        ddg[m * 64 + t] = dd[t];
        eeg[m * 64 + t] = (t < 63) ? ee[t] : 0.0f;
        tauvg[m * 64 + t] = tauv[t];
    }
}

// ---------------- Kernel 3: 512 parallel 16-block STEQRs ----------------
__global__ __launch_bounds__(64, 1)
void steqr_kernel(float* __restrict__ ddg, const float* __restrict__ eeg,
                  float* __restrict__ zg) {
    const int blk = blockIdx.x;
    const int m = blk >> 2, s = blk & 3;
    const int l = threadIdx.x;
    __shared__ float Zt[16][17];
    float dreg = (l < 16) ? ddg[m * 64 + 16 * s + l] : 0.0f;
    float ereg = (l < 15) ? eeg[m * 64 + 16 * s + l] : 0.0f;
    if (l < 16)
        for (int j = 0; j < 16; ++j) Zt[l][j] = (l == j) ? 1.0f : 0.0f;
    ssteqr16_reg(dreg, ereg, Zt, l);
    if (l < 16) {
        ddg[m * 64 + 16 * s + l] = dreg;
        for (int j = 0; j < 16; ++j)
            zg[(size_t)m * 4096 + (size_t)(16 * s + l) * 64 + (16 * s + j)] = Zt[l][j];
    }
}

// ---------------- Kernel 4: 256 parallel 32-merges ----------------
__global__ __launch_bounds__(64, 1)
void merge32_kernel(float* __restrict__ ddg, const float* __restrict__ eeg,
                    float* __restrict__ zg, int* __restrict__ indxqg) {
    const int m = blockIdx.x >> 1, q = blockIdx.x & 1;
    const int t = threadIdx.x;
    __shared__ float Zm[32][33], Q2[32][33], Sm[32][33];
    __shared__ float dd[32], zz[32], dl[32], wv[32], zt[32], bsc[2];
    __shared__ float rotc[32], rots[32];
    __shared__ int rotp[32], rotqv[32], indxp_[32], indxq[32], indx_[32], imrg[32], ksh[2];
    if (t < 32) {
        for (int c = 0; c < 32; ++c)
            Zm[t][c] = ((t >> 4) == (c >> 4))
                     ? zg[(size_t)m * 4096 + (size_t)(32 * q + t) * 64 + (32 * q + c)] : 0.0f;
        dd[t] = ddg[m * 64 + 32 * q + t];
        indxq[t] = t & 15;
    }
    __syncthreads();
    float rho = eeg[m * 64 + 15 + 32 * q];
    merge_dev<32>(Zm, Q2, Sm, dd, zz, dl, wv, zt, bsc, ksh, rotc, rots, rotp, rotqv,
                  indxp_, indxq, indx_, imrg, rho, t, 64);
    if (t < 32) {
        for (int c = 0; c < 32; ++c)
            zg[(size_t)m * 4096 + (size_t)(32 * q + t) * 64 + (32 * q + c)] = Zm[t][c];
        ddg[m * 64 + 32 * q + t] = dd[t];
        indxqg[m * 64 + 32 * q + t] = indxq[t];
    }
}

// ---------------- Kernel 5: 64-merge only ----------------
__global__ __launch_bounds__(256, 1)
void merge64_kernel(float* __restrict__ ddg, const float* __restrict__ eeg,
                    float* __restrict__ zg, int* __restrict__ indxqg) {
    const int m = blockIdx.x;
    const int t = threadIdx.x;
    __shared__ float Zm[64][65], Q2[64][65], Sm[64][65];
    __shared__ float dd[64], zz[64], dl[64], wv[64], zt[64], bsc[2];
    __shared__ float rotc[64], rots[64];
    __shared__ int rotp[64], rotqv[64], indxp_[64], indxq[64], indx_[64], imrg[64], ksh[2];
    for (int e = t; e < 4096; e += 256) {
        int r = e >> 6, c = e & 63;
        Zm[r][c] = ((r >> 5) == (c >> 5)) ? zg[(size_t)m * 4096 + e] : 0.0f;
    }
    if (t < 64) { dd[t] = ddg[m * 64 + t]; indxq[t] = indxqg[m * 64 + t]; }
    __syncthreads();
    merge_dev<64>(Zm, Q2, Sm, dd, zz, dl, wv, zt, bsc, ksh, rotc, rots, rotp, rotqv,
                  indxp_, indxq, indx_, imrg, eeg[m * 64 + 31], t, 256);
    for (int e = t; e < 4096; e += 256) zg[(size_t)m * 4096 + e] = Zm[e >> 6][e & 63];
    if (t < 64) { ddg[m * 64 + t] = dd[t]; indxqg[m * 64 + t] = indxq[t]; }
}

// ---------------- Kernel 6: SORMTR (wave-per-16-columns, registers, no barriers) + LN ----------------
__global__ __launch_bounds__(256, 1)
void ormtr_ln_kernel(const float* __restrict__ ddg, const float* __restrict__ zg,
                     const int* __restrict__ indxqg,
                     const float* __restrict__ tauvg, const float* __restrict__ vpackg,
                     const float* __restrict__ onrmg,
                     const float* __restrict__ gma, const float* __restrict__ bta,
                     float* __restrict__ out) {
    const int m = blockIdx.x;
    const int t = threadIdx.x;
    const int lane = t & 63, w = t >> 6;
    __shared__ float Zm[64][65];
    __shared__ float vpack[1953];
    __shared__ float tauv[64], dd[64], dl[64];
    __shared__ int indxq[64];
    if (t < 64) { dd[t] = ddg[m * 64 + t]; indxq[t] = indxqg[m * 64 + t]; tauv[t] = tauvg[m * 64 + t]; }
    for (int e = t; e < 1953; e += 256) vpack[e] = vpackg[(size_t)m * 1953 + e];
    __syncthreads();

    // wave w owns columns w*16 .. w*16+15; lane r holds z[r] in registers
    double zreg[16];
    {
        const float* zp = zg + (size_t)m * 4096 + (size_t)lane * 64 + w * 16;
#pragma unroll
        for (int k = 0; k < 16; ++k) zreg[k] = (double)zp[k];
    }
    // SORMTR('L','L','N'): Z := H(1)...H(62) Z, applied H(62) first. Dot via wsum (reorder OK).
    {
        int off = 1953;
        for (int i = 61; i >= 0; --i) {
            off -= 62 - i;
            double taui = (double)tauv[i];
            if (taui != 0.0) {
                double vr = 0.0;
                if (lane == i + 1) vr = 1.0;
                else if (lane >= i + 2) vr = (double)vpack[off + lane - (i + 2)];
#pragma unroll
                for (int k = 0; k < 16; ++k) {
                    double dot = wsum(vr * zreg[k]) * taui;
                    zreg[k] -= dot * vr;
                }
            }
        }
    }
    // write back to LDS for the column-gather epilogue
#pragma unroll
    for (int k = 0; k < 16; ++k) Zm[lane][w * 16 + k] = (float)zreg[k];
    __syncthreads();

    // ---- epilogue: rows y_i = w ⊙ v_i, LayerNorm, ×1/8 ----
    float onrm = onrmg[m];
    if (t < 64) dl[t] = fmul32(dd[indxq[t]], onrm);
    __syncthreads();
    if (t < 64) {
        int ci = indxq[t];
        double mm_ = 0.0;
        for (int j = 0; j < 64; ++j) mm_ += (double)dl[j] * (double)Zm[j][ci];
        mm_ *= (1.0 / 64.0);
        double va = 0.0;
        for (int j = 0; j < 64; ++j) { double dv = (double)dl[j] * (double)Zm[j][ci] - mm_; va += dv * dv; }
        va *= (1.0 / 64.0);
        double inv = 1.0 / sqrt(va + 1.0e-3);
        const int b = m >> 4, h = m & 15;
        float* op = out + ((size_t)((b * 16 + h) * 64 + t)) * 64;
        for (int j = 0; j < 64; ++j) {
            double yn = ((double)dl[j] * (double)Zm[j][ci] - mm_) * inv;
            op[j] = ((float)yn * gma[j] + bta[j]) * 0.125f;
        }
    }
}

extern "C" void kernel_launch(void* const* d_in, const int* in_sizes, int n_in,
                              void* d_out, int out_size, void* d_ws, size_t ws_size,
                              hipStream_t stream) {
    const float* x     = (const float*)d_in[0];
    const float* gamma = (const float*)d_in[1];
    const float* beta  = (const float*)d_in[2];
    float* out = (float*)d_out;

    float* gws    = (float*)d_ws;           // 128*4096 (gram; later reused as zg)
    float* zg     = gws;                    // alias: gram dead after tridiag
    float* means  = gws + 128 * 4096;       // 128*64
    float* ddg    = means + 128 * 64;       // 128*64
    float* eeg    = ddg + 128 * 64;         // 128*64
    float* tauvg  = eeg + 128 * 64;         // 128*64
    float* onrmg  = tauvg + 128 * 64;       // 128
    float* vpackg = onrmg + 128;            // 128*1953
    int*   indxqg = (int*)(vpackg + 128 * 1953);  // 128*64 ints
    // total ≈ 3.3 MB

    mean3_kernel<<<dim3(128), dim3(64), 0, stream>>>(x, means);
    gram_np_kernel<<<dim3(256), dim3(256), 0, stream>>>(x, means, gws);
    tridiag_kernel<<<dim3(128), dim3(256), 0, stream>>>(gws, ddg, eeg, tauvg, vpackg, onrmg);
    steqr_kernel<<<dim3(512), dim3(64), 0, stream>>>(ddg, eeg, zg);
    merge32_kernel<<<dim3(256), dim3(64), 0, stream>>>(ddg, eeg, zg, indxqg);
    merge64_kernel<<<dim3(128), dim3(256), 0, stream>>>(ddg, eeg, zg, indxqg);
    ormtr_ln_kernel<<<dim3(128), dim3(256), 0, stream>>>(ddg, zg, indxqg,
                                                         tauvg, vpackg, onrmg,
                                                         gamma, beta, out);
}

// Round 16
// 1075.361 us; speedup vs baseline: 1.4052x; 1.4052x over previous
//
#include <hip/hip_runtime.h>
#include <math.h>

#define EPS_S     5.9604645e-08f
#define EPS2_S    3.5527137e-15f
#define SAFMIN_S  1.1754944e-38f
#define EPS_D     1.1102230246251565e-16

// ---------- fp32 exact-op helpers (no FMA contraction) ----------
static __device__ __forceinline__ float fadd32(float a, float b){
#pragma clang fp contract(off)
    return a+b; }
static __device__ __forceinline__ float fsub32(float a, float b){
#pragma clang fp contract(off)
    return a-b; }
static __device__ __forceinline__ float fmul32(float a, float b){
#pragma clang fp contract(off)
    return a*b; }
static __device__ __forceinline__ float fdiv32(float a, float b){
#pragma clang fp contract(off)
    return a/b; }
static __device__ __forceinline__ float fsqrt32(float x){ return sqrtf(x); }

static __device__ __forceinline__ double wsum(double v) {
#pragma unroll
    for (int m = 32; m >= 1; m >>= 1) v += __shfl_xor(v, m, 64);
    return v;
}
// sum across aligned 4-lane group (bit-identical in all 4 lanes)
static __device__ __forceinline__ double qsum4(double v) {
    v += __shfl_xor(v, 1, 64);
    v += __shfl_xor(v, 2, 64);
    return v;
}
static __device__ __forceinline__ float wmaxrf(float v) {
#pragma unroll
    for (int m = 32; m >= 1; m >>= 1) { float o = __shfl_xor(v, m, 64); v = fmaxf(v, o); }
    return v;
}
static __device__ __forceinline__ float slapy2f(float x, float y) {
    float ax = fabsf(x), ay = fabsf(y);
    float w = fmaxf(ax, ay), z = fminf(ax, ay);
    if (z == 0.0f) return w;
    float r = fdiv32(z, w);
    return fmul32(w, fsqrt32(fadd32(1.0f, fmul32(r, r))));
}
static __device__ __forceinline__ double dlapy2(double x, double y) {
    double ax = fabs(x), ay = fabs(y);
    double w = fmax(ax, ay), z = fmin(ax, ay);
    if (z == 0.0) return w;
    double r = z / w;
    return w * sqrt(1.0 + r * r);
}
static __device__ __forceinline__ float fsignf(float a, float b){ return copysignf(fabsf(a), b); }

// LAPACK >= 3.10 slartg, fp32
static __device__ __forceinline__ void slartg(float f, float g, float& cs, float& sn, float& r) {
    if (g == 0.0f)      { cs = 1.0f; sn = 0.0f; r = f; }
    else if (f == 0.0f) { cs = 0.0f; sn = copysignf(1.0f, g); r = fabsf(g); }
    else {
        float d = fsqrt32(fadd32(fmul32(f,f), fmul32(g,g)));
        cs = fdiv32(fabsf(f), d);
        r = copysignf(d, f);
        sn = fdiv32(g, r);
    }
}
static __device__ void slaev2(float a, float b, float c,
                              float& rt1, float& rt2, float& cs1, float& sn1) {
    float sm = fadd32(a,c), df = fsub32(a,c), adf = fabsf(df);
    float tb = fadd32(b,b), ab = fabsf(tb);
    float acmx, acmn;
    if (fabsf(a) > fabsf(c)) { acmx = a; acmn = c; } else { acmx = c; acmn = a; }
    float rt;
    if (adf > ab)      { float q = fdiv32(ab,adf); rt = fmul32(adf, fsqrt32(fadd32(1.0f, fmul32(q,q)))); }
    else if (adf < ab) { float q = fdiv32(adf,ab); rt = fmul32(ab,  fsqrt32(fadd32(1.0f, fmul32(q,q)))); }
    else               rt = fmul32(ab, fsqrt32(2.0f));
    int sgn1;
    if (sm < 0.0f)      { rt1 = fmul32(0.5f, fsub32(sm, rt)); sgn1 = -1;
        rt2 = fsub32(fmul32(fdiv32(acmx,rt1),acmn), fmul32(fdiv32(b,rt1),b)); }
    else if (sm > 0.0f) { rt1 = fmul32(0.5f, fadd32(sm, rt)); sgn1 = 1;
        rt2 = fsub32(fmul32(fdiv32(acmx,rt1),acmn), fmul32(fdiv32(b,rt1),b)); }
    else                { rt1 = fmul32(0.5f, rt); rt2 = fmul32(-0.5f, rt); sgn1 = 1; }
    float cs; int sgn2;
    if (df >= 0.0f) { cs = fadd32(df, rt); sgn2 = 1; } else { cs = fsub32(df, rt); sgn2 = -1; }
    float acs = fabsf(cs);
    if (acs > ab) {
        float ct = fdiv32(-tb, cs);
        sn1 = fdiv32(1.0f, fsqrt32(fadd32(1.0f, fmul32(ct,ct))));
        cs1 = fmul32(ct, sn1);
    } else {
        if (ab == 0.0f) { cs1 = 1.0f; sn1 = 0.0f; }
        else {
            float tn = fdiv32(-cs, tb);
            cs1 = fdiv32(1.0f, fsqrt32(fadd32(1.0f, fmul32(tn,tn))));
            sn1 = fmul32(tn, cs1);
        }
    }
    if (sgn1 == sgn2) { float tn = cs1; cs1 = -sn1; sn1 = tn; }
}
// DLAED5 (K==2): double internals, float outputs
static __device__ void dlaed5(int i, const float* d2f, const float* z2f, double rho,
                              float& dlt1, float& dlt2, float& dlam) {
    double d0 = d2f[0], d1 = d2f[1], z0 = z2f[0], z1 = z2f[1];
    double del = d1 - d0, a, b2, tau2, e1, e2, lam;
    if (i == 0) {
        double w = 1.0 + 2.0 * rho * (z1*z1 - z0*z0) / del;
        if (w > 0.0) {
            a = del + rho * (z0*z0 + z1*z1);
            b2 = rho * z0*z0 * del;
            tau2 = 2.0 * b2 / (a + sqrt(fabs(a*a - 4.0*b2)));
            lam = d0 + tau2; e1 = -z0 / tau2; e2 = z1 / (del - tau2);
        } else {
            a = -del + rho * (z0*z0 + z1*z1);
            b2 = rho * z1*z1 * del;
            if (a > 0.0) tau2 = -2.0*b2 / (a + sqrt(a*a + 4.0*b2));
            else         tau2 = (a - sqrt(a*a + 4.0*b2)) / 2.0;
            lam = d1 + tau2; e1 = -z0 / (del + tau2); e2 = -z1 / tau2;
        }
    } else {
        a = -del + rho * (z0*z0 + z1*z1);
        b2 = rho * z1*z1 * del;
        if (a > 0.0) tau2 = (a + sqrt(a*a + 4.0*b2)) / 2.0;
        else         tau2 = 2.0*b2 / (-a + sqrt(a*a + 4.0*b2));
        lam = d1 + tau2; e1 = -z0 / (del + tau2); e2 = -z1 / tau2;
    }
    double nrm = sqrt(e1*e1 + e2*e2);
    dlt1 = (float)(e1 / nrm); dlt2 = (float)(e2 / nrm); dlam = (float)lam;
}
// serial safeguarded Newton-bisection secular solver (r14 version; used by merge32)
static __device__ void secular_solve(int K, int jj, const float* dlf, const float* wvf, double rho,
                                     int& io, double& tau) {
    if (jj < K - 1) {
        double dj = dlf[jj], dj1 = dlf[jj + 1];
        double mid = 0.5 * (dj + dj1);
        double f = 1.0;
        for (int i = 0; i < K; ++i) {
            double wv = wvf[i];
            double inv = 1.0 / ((double)dlf[i] - mid);
            f += rho * wv * wv * inv;
        }
        bool orgati = (f > 0.0);
        io = orgati ? jj : jj + 1;
        double dio = dlf[io];
        double lo, hi;
        if (orgati) { lo = 0.0; hi = mid - dj; }
        else        { lo = mid - dj1; hi = 0.0; }
        tau = 0.5 * (lo + hi);
        for (int it = 0; it < 30; ++it) {
            double fv = 1.0, fp = 0.0;
            for (int i = 0; i < K; ++i) {
                double del = ((double)dlf[i] - dio) - tau;
                double wv = wvf[i];
                double inv = 1.0 / del;
                double r1 = rho * wv * wv * inv;
                fv += r1; fp += r1 * inv;
            }
            if (fv < 0.0) lo = tau; else hi = tau;
            double tn = tau - fv / fp;
            if (!(tn > lo && tn < hi)) tn = 0.5 * (lo + hi);
            double step = fabs(tn - tau);
            tau = tn;
            if (step <= 1.0e-9 * (fabs(dio) + fabs(tau))) break;
            if ((hi - lo) <= 1.0e-11 * (fabs(dio) + fabs(tau))) break;
        }
    } else {
        io = K - 1;
        double dio = dlf[io];
        double zsum = 0.0;
        for (int i = 0; i < K; ++i) { double wv = wvf[i]; zsum += wv * wv; }
        double lo = 0.0, hi = rho * zsum;
        for (int rep = 0; rep < 4; ++rep) {
            double fv = 1.0;
            for (int i = 0; i < K; ++i) {
                double wv = wvf[i];
                fv += rho * wv * wv / (((double)dlf[i] - dio) - hi);
            }
            if (fv >= 0.0) break;
            hi *= 2.0;
        }
        tau = 0.5 * (lo + hi);
        for (int it = 0; it < 30; ++it) {
            double fv = 1.0, fp = 0.0;
            for (int i = 0; i < K; ++i) {
                double del = ((double)dlf[i] - dio) - tau;
                double wv = wvf[i];
                double inv = 1.0 / del;
                double r1 = rho * wv * wv * inv;
                fv += r1; fp += r1 * inv;
            }
            if (fv < 0.0) lo = tau; else hi = tau;
            double tn = tau - fv / fp;
            if (!(tn > lo && tn < hi)) tn = 0.5 * (lo + hi);
            double step = fabs(tn - tau);
            tau = tn;
            if (step <= 1.0e-9 * (fabs(dio) + fabs(tau))) break;
            if ((hi - lo) <= 1.0e-11 * (fabs(dio) + fabs(tau))) break;
        }
    }
}
// 4-lanes-per-root secular solver: sublane s handles terms s, s+4, ...; qsum4 reduce.
// Identical decisions across the 4 lanes (bit-identical reductions). Value-path reorder only.
static __device__ void secular_solve4(int K, int jj, int s, const float* dlf, const float* wvf,
                                      double rho, int& io, double& tau) {
    if (jj < K - 1) {
        double dj = dlf[jj], dj1 = dlf[jj + 1];
        double mid = 0.5 * (dj + dj1);
        double fpart = 0.0;
        for (int i = s; i < K; i += 4) {
            double wv = wvf[i];
            fpart += wv * wv / ((double)dlf[i] - mid);
        }
        double f = 1.0 + rho * qsum4(fpart);
        bool orgati = (f > 0.0);
        io = orgati ? jj : jj + 1;
        double dio = dlf[io];
        double lo, hi;
        if (orgati) { lo = 0.0; hi = mid - dj; }
        else        { lo = mid - dj1; hi = 0.0; }
        tau = 0.5 * (lo + hi);
        for (int it = 0; it < 30; ++it) {
            double fvp = 0.0, fpp = 0.0;
            for (int i = s; i < K; i += 4) {
                double del = ((double)dlf[i] - dio) - tau;
                double wv = wvf[i];
                double inv = 1.0 / del;
                double r1 = wv * wv * inv;
                fvp += r1; fpp += r1 * inv;
            }
            double fv = 1.0 + rho * qsum4(fvp);
            double fp = rho * qsum4(fpp);
            if (fv < 0.0) lo = tau; else hi = tau;
            double tn = tau - fv / fp;
            if (!(tn > lo && tn < hi)) tn = 0.5 * (lo + hi);
            double step = fabs(tn - tau);
            tau = tn;
            if (step <= 1.0e-9 * (fabs(dio) + fabs(tau))) break;
            if ((hi - lo) <= 1.0e-11 * (fabs(dio) + fabs(tau))) break;
        }
    } else {
        io = K - 1;
        double dio = dlf[io];
        double zp = 0.0;
        for (int i = s; i < K; i += 4) { double wv = wvf[i]; zp += wv * wv; }
        double zsum = qsum4(zp);
        double lo = 0.0, hi = rho * zsum;
        for (int rep = 0; rep < 4; ++rep) {
            double fvp = 0.0;
            for (int i = s; i < K; i += 4) {
                double wv = wvf[i];
                fvp += wv * wv / (((double)dlf[i] - dio) - hi);
            }
            double fv = 1.0 + rho * qsum4(fvp);
            if (fv >= 0.0) break;
            hi *= 2.0;
        }
        tau = 0.5 * (lo + hi);
        for (int it = 0; it < 30; ++it) {
            double fvp = 0.0, fpp = 0.0;
            for (int i = s; i < K; i += 4) {
                double del = ((double)dlf[i] - dio) - tau;
                double wv = wvf[i];
                double inv = 1.0 / del;
                double r1 = wv * wv * inv;
                fvp += r1; fpp += r1 * inv;
            }
            double fv = 1.0 + rho * qsum4(fvp);
            double fp = rho * qsum4(fpp);
            if (fv < 0.0) lo = tau; else hi = tau;
            double tn = tau - fv / fp;
            if (!(tn > lo && tn < hi)) tn = 0.5 * (lo + hi);
            double step = fabs(tn - tau);
            tau = tn;
            if (step <= 1.0e-9 * (fabs(dio) + fabs(tau))) break;
            if ((hi - lo) <= 1.0e-11 * (fabs(dio) + fabs(tau))) break;
        }
    }
}

// ---------------- SSTEQR (compz='I'), register+shuffle state, 16x17 LDS Z-tile ----------------
static __device__ void ssteqr16_reg(float& dreg, float& ereg, float (*Zt)[17], int l) {
    const int nn = 16;
    const int nmaxit = nn * 30;
    float wcreg = 0.0f, wsreg = 0.0f;
#define D16(i) __shfl(dreg, (i), 64)
#define E16(i) __shfl(ereg, (i), 64)
    int jtot = 0, l1 = 0;
    while (l1 <= nn - 1) {
        if (l1 > 0) { if (l == l1 - 1) ereg = 0.0f; }
        int m;
        for (m = l1; m <= nn - 2; ++m) {
            float em = E16(m);
            float tst = fabsf(em);
            if (tst == 0.0f) break;
            if (tst <= fmul32(fmul32(fsqrt32(fabsf(D16(m))), fsqrt32(fabsf(D16(m+1)))), EPS_S)) {
                if (l == m) ereg = 0.0f;
                break;
            }
        }
        int lq = l1, lend = m;
        l1 = m + 1;
        if (lend == lq) continue;
        if (fabsf(D16(lend)) < fabsf(D16(lq))) { int sw = lq; lq = lend; lend = sw; }
        if (lend > lq) {
            // ---- QL ----
            for (;;) {
                int mm = lend;
                if (lq != lend) {
                    for (int q = lq; q <= lend - 1; ++q) {
                        float eq = E16(q);
                        float tst = fmul32(eq, eq);
                        if (tst <= fadd32(fmul32(fmul32(EPS2_S, fabsf(D16(q))), fabsf(D16(q+1))), SAFMIN_S)) { mm = q; break; }
                    }
                }
                if (mm < lend) { if (l == mm) ereg = 0.0f; }
                float p = D16(lq);
                if (mm == lq) { lq = lq + 1; if (lq > lend) break; continue; }
                if (mm == lq + 1) {
                    float rt1, rt2, c, s;
                    slaev2(D16(lq), E16(lq), D16(lq + 1), rt1, rt2, c, s);
                    if (l < nn) {
                        float z1 = Zt[l][lq], z2 = Zt[l][lq + 1];
                        Zt[l][lq + 1] = fsub32(fmul32(c, z2), fmul32(s, z1));
                        Zt[l][lq]     = fadd32(fmul32(s, z2), fmul32(c, z1));
                    }
                    if (l == lq)     { dreg = rt1; ereg = 0.0f; }
                    if (l == lq + 1) dreg = rt2;
                    lq += 2;
                    if (lq > lend) break;
                    continue;
                }
                if (jtot == nmaxit) break;
                jtot++;
                float g = fdiv32(fsub32(D16(lq + 1), p), fmul32(2.0f, E16(lq)));
                float r = slapy2f(g, 1.0f);
                g = fadd32(fsub32(D16(mm), p), fdiv32(E16(lq), fadd32(g, fsignf(r, g))));
                float s = 1.0f, c = 1.0f;
                p = 0.0f;
                for (int i = mm - 1; i >= lq; --i) {
                    float ei = E16(i);
                    float f = fmul32(s, ei), bq = fmul32(c, ei);
                    slartg(g, f, c, s, r);
                    if (i != mm - 1) { if (l == i + 1) ereg = r; }
                    g = fsub32(D16(i + 1), p);
                    r = fadd32(fmul32(fsub32(D16(i), g), s), fmul32(fmul32(2.0f, c), bq));
                    p = fmul32(s, r);
                    if (l == i + 1) dreg = fadd32(g, p);
                    g = fsub32(fmul32(c, r), bq);
                    if (l == i) { wcreg = c; wsreg = -s; }
                }
                for (int j = mm - 1; j >= lq; --j) {
                    float cj = __shfl(wcreg, j, 64), sj = __shfl(wsreg, j, 64);
                    if (l < nn) {
                        float z1 = Zt[l][j], z2 = Zt[l][j + 1];
                        Zt[l][j + 1] = fsub32(fmul32(cj, z2), fmul32(sj, z1));
                        Zt[l][j]     = fadd32(fmul32(sj, z2), fmul32(cj, z1));
                    }
                }
                if (l == lq) { dreg = fsub32(dreg, p); ereg = g; }
            }
        } else {
            // ---- QR ----
            for (;;) {
                int mm = lend;
                if (lq != lend) {
                    for (int q = lq; q >= lend + 1; --q) {
                        float eq1 = E16(q - 1);
                        float tst = fmul32(eq1, eq1);
                        if (tst <= fadd32(fmul32(fmul32(EPS2_S, fabsf(D16(q))), fabsf(D16(q-1))), SAFMIN_S)) { mm = q; break; }
                    }
                }
                if (mm > lend) { if (l == mm - 1) ereg = 0.0f; }
                float p = D16(lq);
                if (mm == lq) { lq = lq - 1; if (lq < lend) break; continue; }
                if (mm == lq - 1) {
                    float rt1, rt2, c, s;
                    slaev2(D16(lq - 1), E16(lq - 1), D16(lq), rt1, rt2, c, s);
                    if (l < nn) {
                        float z1 = Zt[l][lq - 1], z2 = Zt[l][lq];
                        Zt[l][lq]     = fsub32(fmul32(c, z2), fmul32(s, z1));
                        Zt[l][lq - 1] = fadd32(fmul32(s, z2), fmul32(c, z1));
                    }
                    if (l == lq - 1) { dreg = rt1; ereg = 0.0f; }
                    if (l == lq)     dreg = rt2;
                    lq -= 2;
                    if (lq < lend) break;
                    continue;
                }
                if (jtot == nmaxit) break;
                jtot++;
                float g = fdiv32(fsub32(D16(lq - 1), p), fmul32(2.0f, E16(lq - 1)));
                float r = slapy2f(g, 1.0f);
                g = fadd32(fsub32(D16(mm), p), fdiv32(E16(lq - 1), fadd32(g, fsignf(r, g))));
                float s = 1.0f, c = 1.0f;
                p = 0.0f;
                for (int i = mm; i <= lq - 1; ++i) {
                    float ei = E16(i);
                    float f = fmul32(s, ei), bq = fmul32(c, ei);
                    slartg(g, f, c, s, r);
                    if (i != mm) { if (l == i - 1) ereg = r; }
                    g = fsub32(D16(i), p);
                    r = fadd32(fmul32(fsub32(D16(i + 1), g), s), fmul32(fmul32(2.0f, c), bq));
                    p = fmul32(s, r);
                    if (l == i) dreg = fadd32(g, p);
                    g = fsub32(fmul32(c, r), bq);
                    if (l == i) { wcreg = c; wsreg = s; }
                }
                for (int j = mm; j <= lq - 1; ++j) {
                    float cj = __shfl(wcreg, j, 64), sj = __shfl(wsreg, j, 64);
                    if (l < nn) {
                        float z1 = Zt[l][j], z2 = Zt[l][j + 1];
                        Zt[l][j + 1] = fsub32(fmul32(cj, z2), fmul32(sj, z1));
                        Zt[l][j]     = fadd32(fmul32(sj, z2), fmul32(cj, z1));
                    }
                }
                if (l == lq)     dreg = fsub32(dreg, p);
                if (l == lq - 1) ereg = g;
            }
        }
    }
    // selection sort ascending + column swaps
    for (int ii = 1; ii <= nn - 1; ++ii) {
        int i = ii - 1, k = i;
        float p = D16(i);
        for (int j = ii; j <= nn - 1; ++j) { float dj = D16(j); if (dj < p) { k = j; p = dj; } }
        if (k != i) {
            float di_old = D16(i);
            if (l == k) dreg = di_old;
            if (l == i) dreg = p;
            if (l < nn) {
                float tz = Zt[l][i];
                Zt[l][i] = Zt[l][k];
                Zt[l][k] = tz;
            }
        }
    }
#undef D16
#undef E16
}

// ---------------- merge (SLAED1+2+3), templated on size; decision arithmetic preserved ----------------
template<int NM>
static __device__ void merge_dev(float (*Zm)[NM + 1], float (*Q2)[NM + 1], float (*Sm)[NM + 1],
                                 float* dd, float* zz, float* dl, float* wv, float* zt,
                                 float* bsc, int* ksh,
                                 float* rotc, float* rots, int* rotp, int* rotq,
                                 int* indxp_, int* indxq, int* indx_, int* imrg,
                                 float rho_in, int t, int nthreads) {
    const int nm = NM, n1 = NM / 2, n2 = NM - n1;
    const int row = t & 63;
    const int nw = nthreads >> 6;
    const int wq = t >> 6;
    if (t < n1)      zz[t] = Zm[n1 - 1][t];
    else if (t < nm) zz[t] = Zm[n1][t];
    __syncthreads();
    float rho = rho_in;
    if (rho < 0.0f) { if (t >= n1 && t < nm) zz[t] = -zz[t]; }
    {
        float tscal = fdiv32(1.0f, fsqrt32(2.0f));
        if (t < nm) zz[t] = fmul32(zz[t], tscal);
    }
    rho = fabsf(fmul32(2.0f, rho));
    if (t >= n1 && t < nm) indxq[t] += n1;
    __syncthreads();
    if (t < nm) dl[t] = dd[indxq[t]];
    __syncthreads();
    if (t == 0) {  // SLAMRG(n1,n2) -> imrg
        int n1sv = n1, n2sv = n2, ind1 = 0, ind2 = n1, iw = 0;
        while (n1sv > 0 && n2sv > 0) {
            if (dl[ind1] <= dl[ind2]) { imrg[iw++] = ind1++; n1sv--; }
            else                      { imrg[iw++] = ind2++; n2sv--; }
        }
        while (n1sv-- > 0) imrg[iw++] = ind1++;
        while (n2sv-- > 0) imrg[iw++] = ind2++;
    }
    __syncthreads();
    if (t < nm) indx_[t] = indxq[imrg[t]];
    __syncthreads();
    {
        float zv = (t < nm) ? fabsf(zz[t]) : 0.0f;
        float dv = (t < nm) ? fabsf(dd[t]) : 0.0f;
        float zm_w = wmaxrf(zv), dm_w = wmaxrf(dv);
        if (t == 0) { bsc[0] = zm_w; bsc[1] = dm_w; }
    }
    __syncthreads();
    float zmax = bsc[0], dmax = bsc[1];
    float tol = fmul32(4.76837158203125e-7f /* 8*2^-24 */, fmaxf(dmax, zmax));
    if (fmul32(rho, zmax) <= tol) {  // everything deflated
        if (row < nm) for (int j = wq; j < nm; j += nw) Q2[row][j] = Zm[row][indx_[j]];
        if (t == 0) for (int j = 0; j < nm; ++j) dl[j] = dd[indx_[j]];
        __syncthreads();
        if (row < nm) for (int j = wq; j < nm; j += nw) Zm[row][j] = Q2[row][j];
        if (t == 0) for (int j = 0; j < nm; ++j) { dd[j] = dl[j]; indxq[j] = j; }
        __syncthreads();
        return;
    }
    // ---- deflation scan (SLAED2): t0-serial decisions, register-carried pj state ----
    if (t == 0) {
        int k2 = nm + 1, K = 0, nrot = 0;
        int j = 0, pj = -1;
        float zpj = 0.0f, dpj = 0.0f;
        for (; j < nm; ++j) {
            int nj = indx_[j];
            if (fmul32(rho, fabsf(zz[nj])) <= tol) { k2--; indxp_[k2 - 1] = nj; }
            else { pj = nj; zpj = zz[nj]; dpj = dd[nj]; break; }
        }
        if (pj >= 0) {
            for (;;) {
                j++;
                if (j >= nm) break;
                int nj = indx_[j];
                float znj = zz[nj];
                if (fmul32(rho, fabsf(znj)) <= tol) { k2--; indxp_[k2 - 1] = nj; }
                else {
                    float sgv = zpj, cgv = znj;
                    float tg = slapy2f(cgv, sgv);
                    float dnj = dd[nj];
                    float tdf = fsub32(dnj, dpj);
                    float cg = fdiv32(cgv, tg), sg = fdiv32(-sgv, tg);
                    if (fabsf(fmul32(fmul32(tdf, cg), sg)) <= tol) {
                        zz[nj] = tg; zz[pj] = 0.0f;
                        rotc[nrot] = cg; rots[nrot] = sg; rotp[nrot] = pj; rotq[nrot] = nj; nrot++;
                        float c2 = fmul32(cg, cg), s2 = fmul32(sg, sg);
                        float tv  = fadd32(fmul32(dpj, c2), fmul32(dnj, s2));
                        float dnn = fadd32(fmul32(dpj, s2), fmul32(dnj, c2));
                        dd[nj] = dnn; dd[pj] = tv;
                        k2--;
                        int ii = 1;
                        for (;;) {
                            if (k2 + ii <= nm) {
                                if (tv < dd[indxp_[k2 + ii - 1]]) {
                                    indxp_[k2 + ii - 2] = indxp_[k2 + ii - 1];
                                    indxp_[k2 + ii - 1] = pj;
                                    ii++;
                                } else { indxp_[k2 + ii - 2] = pj; break; }
                            } else { indxp_[k2 + ii - 2] = pj; break; }
                        }
                        pj = nj; zpj = tg; dpj = dnn;
                    } else {
                        dl[K] = dpj; wv[K] = zpj; indxp_[K] = pj;
                        K++;
                        pj = nj; zpj = znj; dpj = dnj;
                    }
                }
            }
            dl[K] = dpj; wv[K] = zpj; indxp_[K] = pj;
            K++;
        }
        ksh[0] = K; ksh[1] = nrot;
    }
    __syncthreads();
    const int K = ksh[0], nrot = ksh[1];
    if (t < nm) {
        for (int q = 0; q < nrot; ++q) {
            int pjq = rotp[q], njq = rotq[q];
            float cg = rotc[q], sg = rots[q];
            float q1 = Zm[t][pjq], q2v = Zm[t][njq];
            Zm[t][pjq] = fadd32(fmul32(cg, q1), fmul32(sg, q2v));
            Zm[t][njq] = fsub32(fmul32(cg, q2v), fmul32(sg, q1));
        }
    }
    __syncthreads();
    if (row < nm) for (int j = wq; j < nm; j += nw) Q2[row][j] = Zm[row][indxp_[j]];
    if (t == 0) for (int j = K; j < nm; ++j) dl[j] = dd[indxp_[j]];
    __syncthreads();
    if (row < nm) for (int j = K + wq; j < nm; j += nw) Zm[row][j] = Q2[row][j];
    if (t == 0) for (int j = K; j < nm; ++j) dd[j] = dl[j];
    __syncthreads();
    // ---- SLAED3 ----
    if (K == 1) {
        if (t == 0) dd[0] = (float)((double)dl[0] + (double)rho * (double)wv[0] * (double)wv[0]);
        if (t < nm) Zm[t][0] = Q2[t][0];
    } else if (K == 2) {
        float v00, v10, v01, v11, r0, r1;
        dlaed5(0, dl, wv, (double)rho, v00, v10, r0);
        dlaed5(1, dl, wv, (double)rho, v01, v11, r1);
        if (t == 0) { dd[0] = r0; dd[1] = r1; }
        if (t < nm) {
            float a0 = Q2[t][0], a1 = Q2[t][1];
            Zm[t][0] = (float)((double)a0 * v00 + (double)a1 * v10);
            Zm[t][1] = (float)((double)a0 * v01 + (double)a1 * v11);
        }
    } else if (K >= 3) {
        if constexpr (NM == 64) {
            // 4 lanes per root: wave w owns roots 16w..16w+15
            const int lane = t & 63, w = t >> 6;
            const int r = w * 16 + (lane >> 2), s = lane & 3;
            if (r < K) {
                int io = 0; double tauj = 0.0;
                secular_solve4(K, r, s, dl, wv, (double)rho, io, tauj);
                double dio = dl[io];
                for (int i = s; i < K; i += 4)
                    Zm[i][r] = (float)(((double)dl[i] - dio) - tauj);
                if (s == 0) dd[r] = (float)(dio + tauj);
            }
        } else {
            if (t < K) {
                int io = 0; double tauj = 0.0;
                secular_solve(K, t, dl, wv, (double)rho, io, tauj);
                double dio = dl[io];
                for (int i = 0; i < K; ++i)
                    Zm[i][t] = (float)(((double)dl[i] - dio) - tauj);
                dd[t] = (float)(dio + tauj);
            }
        }
        __syncthreads();
        if (t < K) {
            double wn = (double)Zm[t][t];
            for (int j2 = 0; j2 < K; ++j2) {
                if (j2 == t) continue;
                wn *= (double)Zm[t][j2] / ((double)dl[t] - (double)dl[j2]);
            }
            zt[t] = (float)copysign(sqrt(-wn), (double)wv[t]);
        }
        __syncthreads();
        for (int j2 = 0; j2 < K; ++j2) {
            double sv = 0.0;
            if (t < K) sv = (double)zt[t] / (double)Zm[t][j2];
            double nr = sqrt(wsum(sv * sv));
            if (t < K) Sm[t][j2] = (float)(sv / nr);
        }
        __syncthreads();
        if (row < nm) {
            for (int j2 = wq; j2 < K; j2 += nw) {
                double acc = 0.0;
                for (int i = 0; i < K; ++i) acc += (double)Q2[row][i] * (double)Sm[i][j2];
                Zm[row][j2] = (float)acc;
            }
        }
    }
    __syncthreads();
    // ---- INDXQ via SLAMRG(K asc, nm-K desc) ----
    if (t == 0) {
        int n1sv = K, n2sv = nm - K, ind1 = 0, ind2 = nm - 1, iw = 0;
        while (n1sv > 0 && n2sv > 0) {
            if (dd[ind1] <= dd[ind2]) { indxq[iw++] = ind1++; n1sv--; }
            else                      { indxq[iw++] = ind2--; n2sv--; }
        }
        while (n1sv-- > 0) indxq[iw++] = ind1++;
        while (n2sv-- > 0) indxq[iw++] = ind2--;
    }
    __syncthreads();
}

// ---------------- Kernel 0: np-exact means, register-unrolled prefetch (bit-identical chain) ----------------
__global__ __launch_bounds__(64, 1)
void mean3_kernel(const float* __restrict__ x, float* __restrict__ means) {
    const int bh = blockIdx.x, b = bh >> 4, h = bh & 15, t = threadIdx.x;
    const float* xb = x + ((size_t)b * 4096) * 1024 + h * 64 + t;
    float acc = 0.0f;
    for (int s0 = 0; s0 < 4096; s0 += 64) {
        float v[64];
#pragma unroll
        for (int k = 0; k < 64; ++k) v[k] = xb[(size_t)(s0 + k) * 1024];
#pragma unroll
        for (int k = 0; k < 64; ++k) acc = fadd32(acc, v[k]);
    }
    means[bh * 64 + t] = fdiv32(acc, 4096.0f);
}

// ---------------- Kernel 1: np-exact centered Gram, double-buffered ----------------
__global__ __launch_bounds__(256, 1)
void gram_np_kernel(const float* __restrict__ x, const float* __restrict__ means,
                    float* __restrict__ gws) {
    const int t = threadIdx.x;
    const int blk = blockIdx.x;
    const int bh = blk >> 1, half = blk & 1;
    const int b = bh >> 4, h = bh & 15;
    __shared__ float xs[2][64][64];
    __shared__ float meansh[64];
    const float* xb = x + ((size_t)b * 4096) * 1024 + h * 64;
    if (t < 64) meansh[t] = means[bh * 64 + t];
    __syncthreads();

#define LOADTILE(TI, NB) do { \
    _Pragma("unroll") \
    for (int k = 0; k < 16; ++k) { \
        int e = k * 256 + t; \
        int r = e >> 6, c = e & 63; \
        xs[NB][r][c] = fsub32(xb[(size_t)((TI) * 64 + r) * 1024 + c], meansh[c]); \
    } } while (0)

    LOADTILE(0, 0);
    __syncthreads();

    const int i0 = half * 32 + (t >> 4) * 2;
    const int j0 = (t & 15) * 4;
    float a00[4], a01[4], a02[4], a03[4], a10[4], a11[4], a12[4], a13[4];
#pragma unroll
    for (int p = 0; p < 4; ++p) { a00[p]=0;a01[p]=0;a02[p]=0;a03[p]=0;a10[p]=0;a11[p]=0;a12[p]=0;a13[p]=0; }

    for (int tile = 0; tile < 64; ++tile) {
        int buf = tile & 1;
        if (tile + 1 < 64) LOADTILE(tile + 1, buf ^ 1);
        for (int r4 = 0; r4 < 16; ++r4) {
#pragma unroll
            for (int p = 0; p < 4; ++p) {
                int r = r4 * 4 + p;
                float2 xi = *(const float2*)&xs[buf][r][i0];
                float4 xj = *(const float4*)&xs[buf][r][j0];
                a00[p] = fadd32(a00[p], fmul32(xi.x, xj.x));
                a01[p] = fadd32(a01[p], fmul32(xi.x, xj.y));
                a02[p] = fadd32(a02[p], fmul32(xi.x, xj.z));
                a03[p] = fadd32(a03[p], fmul32(xi.x, xj.w));
                a10[p] = fadd32(a10[p], fmul32(xi.y, xj.x));
                a11[p] = fadd32(a11[p], fmul32(xi.y, xj.y));
                a12[p] = fadd32(a12[p], fmul32(xi.y, xj.z));
                a13[p] = fadd32(a13[p], fmul32(xi.y, xj.w));
            }
        }
        __syncthreads();
    }
#undef LOADTILE
    float* gp = gws + (size_t)bh * 4096;
    gp[(i0 + 0) * 64 + j0 + 0] = fadd32(fadd32(a00[0], a00[1]), fadd32(a00[2], a00[3]));
    gp[(i0 + 0) * 64 + j0 + 1] = fadd32(fadd32(a01[0], a01[1]), fadd32(a01[2], a01[3]));
    gp[(i0 + 0) * 64 + j0 + 2] = fadd32(fadd32(a02[0], a02[1]), fadd32(a02[2], a02[3]));
    gp[(i0 + 0) * 64 + j0 + 3] = fadd32(fadd32(a03[0], a03[1]), fadd32(a03[2], a03[3]));
    gp[(i0 + 1) * 64 + j0 + 0] = fadd32(fadd32(a10[0], a10[1]), fadd32(a10[2], a10[3]));
    gp[(i0 + 1) * 64 + j0 + 1] = fadd32(fadd32(a11[0], a11[1]), fadd32(a11[2], a11[3]));
    gp[(i0 + 1) * 64 + j0 + 2] = fadd32(fadd32(a12[0], a12[1]), fadd32(a12[2], a12[3]));
    gp[(i0 + 1) * 64 + j0 + 3] = fadd32(fadd32(a13[0], a13[1]), fadd32(a13[2], a13[3]));
}

// ---------------- Kernel 2: SSYTD2 + scale + tears -> global ----------------
__global__ __launch_bounds__(256, 1)
void tridiag_kernel(const float* __restrict__ gws, float* __restrict__ ddg,
                    float* __restrict__ eeg, float* __restrict__ tauvg,
                    float* __restrict__ vpackg, float* __restrict__ onrmg) {
    __shared__ float Am[64][65];
    __shared__ float tauv[64], dd[64], ee[64], vvv[64], www[64];
    const int t = threadIdx.x;
    const int m = blockIdx.x;
    {
        const float* gp = gws + (size_t)m * 4096;
        for (int e = t; e < 4096; e += 256) Am[e >> 6][e & 63] = gp[e];
    }
    __syncthreads();
    for (int i = 0; i <= 62; ++i) {
        double taui = 0.0;
        if (t < 64) {
            double alpha = (double)Am[i + 1][i];
            double px = (t >= i + 2) ? (double)Am[t][i] : 0.0;
            double xnorm = sqrt(wsum(px * px));
            double beta = alpha;
            if (xnorm != 0.0) {
                beta = -copysign(dlapy2(alpha, xnorm), alpha);
                taui = (beta - alpha) / beta;
                double rs = 1.0 / (alpha - beta);
                if (t >= i + 2) Am[t][i] = (float)((double)Am[t][i] * rs);
            }
            if (t == 0) { ee[i] = (float)beta; tauv[i] = (float)taui; }
        }
        __syncthreads();
        float taub = tauv[i];
        if (taub != 0.0f) {
            if (t < 64 && t >= i + 1) vvv[t] = (t == i + 1) ? 1.0f : Am[t][i];
            __syncthreads();
            if (t < 64) {
                double wr = 0.0;
                if (t >= i + 1) {
                    for (int c = i + 1; c < 64; ++c) wr += (double)Am[t][c] * (double)vvv[c];
                    wr *= taui;
                }
                double dotwv = wsum((t >= i + 1) ? wr * (double)vvv[t] : 0.0);
                double alp2 = -0.5 * taui * dotwv;
                if (t >= i + 1) www[t] = (float)(wr + alp2 * (double)vvv[t]);
            }
            __syncthreads();
            {   // rank-2 update parallel over all 256 threads (elementwise, bit-identical)
                int r = t & 63, w4 = t >> 6;
                if (r >= i + 1) {
                    double vt = vvv[r], wt = www[r];
                    for (int c = i + 1 + w4; c < 64; c += 4)
                        Am[r][c] = (float)((double)Am[r][c] - vt * (double)www[c] - wt * (double)vvv[c]);
                }
            }
            __syncthreads();
        } else {
            __syncthreads();
        }
        if (t == 0) dd[i] = Am[i][i];
    }
    if (t == 0) dd[63] = Am[63][63];
    __syncthreads();
    if (t < 64) {   // pack reflectors direct to global
        int off = 0;
        for (int i = 0; i <= 61; ++i) {
            if (t >= i + 2) vpackg[(size_t)m * 1953 + off + t - (i + 2)] = Am[t][i];
            off += 62 - i;
        }
    }
    if (t < 64) {   // scale
        float onval = fmaxf(fabsf(dd[t]), (t < 63) ? fabsf(ee[t]) : 0.0f);
        float onrm = wmaxrf(onval);
        float mul = fdiv32(1.0f, onrm);
        dd[t] = fmul32(dd[t], mul);
        if (t < 63) ee[t] = fmul32(ee[t], mul);
        if (t == 0) onrmg[m] = onrm;
    }
    __syncthreads();
    if (t == 0) {   // rank-one tears
        int bnds[3] = {15, 31, 47};
        for (int q = 0; q < 3; ++q) {
            int bd = bnds[q];
            float ab = fabsf(ee[bd]);
            dd[bd]     = fsub32(dd[bd], ab);
            dd[bd + 1] = fsub32(dd[bd + 1], ab);
        }
    }
    __syncthreads();
    if (t < 64) {
        ddg[m * 64 + t] = dd[t];
        eeg[m * 64 + t] = (t < 63) ? ee[t] : 0.0f;
        tauvg[m * 64 + t] = tauv[t];
    }
}

// ---------------- Kernel 3: 512 parallel 16-block STEQRs ----------------
__global__ __launch_bounds__(64, 1)
void steqr_kernel(float* __restrict__ ddg, const float* __restrict__ eeg,
                  float* __restrict__ zg) {
    const int blk = blockIdx.x;
    const int m = blk >> 2, s = blk & 3;
    const int l = threadIdx.x;
    __shared__ float Zt[16][17];
    float dreg = (l < 16) ? ddg[m * 64 + 16 * s + l] : 0.0f;
    float ereg = (l < 15) ? eeg[m * 64 + 16 * s + l] : 0.0f;
    if (l < 16)
        for (int j = 0; j < 16; ++j) Zt[l][j] = (l == j) ? 1.0f : 0.0f;
    ssteqr16_reg(dreg, ereg, Zt, l);
    if (l < 16) {
        ddg[m * 64 + 16 * s + l] = dreg;
        for (int j = 0; j < 16; ++j)
            zg[(size_t)m * 4096 + (size_t)(16 * s + l) * 64 + (16 * s + j)] = Zt[l][j];
    }
}

// ---------------- Kernel 4: 256 parallel 32-merges ----------------
__global__ __launch_bounds__(64, 1)
void merge32_kernel(float* __restrict__ ddg, const float* __restrict__ eeg,
                    float* __restrict__ zg, int* __restrict__ indxqg) {
    const int m = blockIdx.x >> 1, q = blockIdx.x & 1;
    const int t = threadIdx.x;
    __shared__ float Zm[32][33], Q2[32][33], Sm[32][33];
    __shared__ float dd[32], zz[32], dl[32], wv[32], zt[32], bsc[2];
    __shared__ float rotc[32], rots[32];
    __shared__ int rotp[32], rotqv[32], indxp_[32], indxq[32], indx_[32], imrg[32], ksh[2];
    if (t < 32) {
        for (int c = 0; c < 32; ++c)
            Zm[t][c] = ((t >> 4) == (c >> 4))
                     ? zg[(size_t)m * 4096 + (size_t)(32 * q + t) * 64 + (32 * q + c)] : 0.0f;
        dd[t] = ddg[m * 64 + 32 * q + t];
        indxq[t] = t & 15;
    }
    __syncthreads();
    float rho = eeg[m * 64 + 15 + 32 * q];
    merge_dev<32>(Zm, Q2, Sm, dd, zz, dl, wv, zt, bsc, ksh, rotc, rots, rotp, rotqv,
                  indxp_, indxq, indx_, imrg, rho, t, 64);
    if (t < 32) {
        for (int c = 0; c < 32; ++c)
            zg[(size_t)m * 4096 + (size_t)(32 * q + t) * 64 + (32 * q + c)] = Zm[t][c];
        ddg[m * 64 + 32 * q + t] = dd[t];
        indxqg[m * 64 + 32 * q + t] = indxq[t];
    }
}

// ---------------- Kernel 5: 64-merge only ----------------
__global__ __launch_bounds__(256, 1)
void merge64_kernel(float* __restrict__ ddg, const float* __restrict__ eeg,
                    float* __restrict__ zg, int* __restrict__ indxqg) {
    const int m = blockIdx.x;
    const int t = threadIdx.x;
    __shared__ float Zm[64][65], Q2[64][65], Sm[64][65];
    __shared__ float dd[64], zz[64], dl[64], wv[64], zt[64], bsc[2];
    __shared__ float rotc[64], rots[64];
    __shared__ int rotp[64], rotqv[64], indxp_[64], indxq[64], indx_[64], imrg[64], ksh[2];
    for (int e = t; e < 4096; e += 256) {
        int r = e >> 6, c = e & 63;
        Zm[r][c] = ((r >> 5) == (c >> 5)) ? zg[(size_t)m * 4096 + e] : 0.0f;
    }
    if (t < 64) { dd[t] = ddg[m * 64 + t]; indxq[t] = indxqg[m * 64 + t]; }
    __syncthreads();
    merge_dev<64>(Zm, Q2, Sm, dd, zz, dl, wv, zt, bsc, ksh, rotc, rots, rotp, rotqv,
                  indxp_, indxq, indx_, imrg, eeg[m * 64 + 31], t, 256);
    for (int e = t; e < 4096; e += 256) zg[(size_t)m * 4096 + e] = Zm[e >> 6][e & 63];
    if (t < 64) { ddg[m * 64 + t] = dd[t]; indxqg[m * 64 + t] = indxq[t]; }
}

// ---------------- Kernel 6: SORMTR (wave-per-16-columns, registers, no barriers) + LN ----------------
__global__ __launch_bounds__(256, 1)
void ormtr_ln_kernel(const float* __restrict__ ddg, const float* __restrict__ zg,
                     const int* __restrict__ indxqg,
                     const float* __restrict__ tauvg, const float* __restrict__ vpackg,
                     const float* __restrict__ onrmg,
                     const float* __restrict__ gma, const float* __restrict__ bta,
                     float* __restrict__ out) {
    const int m = blockIdx.x;
    const int t = threadIdx.x;
    const int lane = t & 63, w = t >> 6;
    __shared__ float Zm[64][65];
    __shared__ float vpack[1953];
    __shared__ float tauv[64], dd[64], dl[64];
    __shared__ int indxq[64];
    if (t < 64) { dd[t] = ddg[m * 64 + t]; indxq[t] = indxqg[m * 64 + t]; tauv[t] = tauvg[m * 64 + t]; }
    for (int e = t; e < 1953; e += 256) vpack[e] = vpackg[(size_t)m * 1953 + e];
    __syncthreads();

    // wave w owns columns w*16 .. w*16+15; lane r holds z[r] in registers
    double zreg[16];
    {
        const float* zp = zg + (size_t)m * 4096 + (size_t)lane * 64 + w * 16;
#pragma unroll
        for (int k = 0; k < 16; ++k) zreg[k] = (double)zp[k];
    }
    // SORMTR('L','L','N'): Z := H(1)...H(62) Z, applied H(62) first. Dot via wsum (reorder OK).
    {
        int off = 1953;
        for (int i = 61; i >= 0; --i) {
            off -= 62 - i;
            double taui = (double)tauv[i];
            if (taui != 0.0) {
                double vr = 0.0;
                if (lane == i + 1) vr = 1.0;
                else if (lane >= i + 2) vr = (double)vpack[off + lane - (i + 2)];
#pragma unroll
                for (int k = 0; k < 16; ++k) {
                    double dot = wsum(vr * zreg[k]) * taui;
                    zreg[k] -= dot * vr;
                }
            }
        }
    }
    // write back to LDS for the column-gather epilogue
#pragma unroll
    for (int k = 0; k < 16; ++k) Zm[lane][w * 16 + k] = (float)zreg[k];
    __syncthreads();

    // ---- epilogue: rows y_i = w ⊙ v_i, LayerNorm, ×1/8 ----
    float onrm = onrmg[m];
    if (t < 64) dl[t] = fmul32(dd[indxq[t]], onrm);
    __syncthreads();
    if (t < 64) {
        int ci = indxq[t];
        double mm_ = 0.0;
        for (int j = 0; j < 64; ++j) mm_ += (double)dl[j] * (double)Zm[j][ci];
        mm_ *= (1.0 / 64.0);
        double va = 0.0;
        for (int j = 0; j < 64; ++j) { double dv = (double)dl[j] * (double)Zm[j][ci] - mm_; va += dv * dv; }
        va *= (1.0 / 64.0);
        double inv = 1.0 / sqrt(va + 1.0e-3);
        const int b = m >> 4, h = m & 15;
        float* op = out + ((size_t)((b * 16 + h) * 64 + t)) * 64;
        for (int j = 0; j < 64; ++j) {
            double yn = ((double)dl[j] * (double)Zm[j][ci] - mm_) * inv;
            op[j] = ((float)yn * gma[j] + bta[j]) * 0.125f;
        }
    }
}

extern "C" void kernel_launch(void* const* d_in, const int* in_sizes, int n_in,
                              void* d_out, int out_size, void* d_ws, size_t ws_size,
                              hipStream_t stream) {
    const float* x     = (const float*)d_in[0];
    const float* gamma = (const float*)d_in[1];
    const float* beta  = (const float*)d_in[2];
    float* out = (float*)d_out;

    float* gws    = (float*)d_ws;           // 128*4096 (gram; later reused as zg)
    float* zg     = gws;                    // alias: gram dead after tridiag
    float* means  = gws + 128 * 4096;       // 128*64
    float* ddg    = means + 128 * 64;       // 128*64
    float* eeg    = ddg + 128 * 64;         // 128*64
    float* tauvg  = eeg + 128 * 64;         // 128*64
    float* onrmg  = tauvg + 128 * 64;       // 128
    float* vpackg = onrmg + 128;            // 128*1953
    int*   indxqg = (int*)(vpackg + 128 * 1953);  // 128*64 ints
    // total ≈ 3.3 MB

    mean3_kernel<<<dim3(128), dim3(64), 0, stream>>>(x, means);
    gram_np_kernel<<<dim3(256), dim3(256), 0, stream>>>(x, means, gws);
    tridiag_kernel<<<dim3(128), dim3(256), 0, stream>>>(gws, ddg, eeg, tauvg, vpackg, onrmg);
    steqr_kernel<<<dim3(512), dim3(64), 0, stream>>>(ddg, eeg, zg);
    merge32_kernel<<<dim3(256), dim3(64), 0, stream>>>(ddg, eeg, zg, indxqg);
    merge64_kernel<<<dim3(128), dim3(256), 0, stream>>>(ddg, eeg, zg, indxqg);
    ormtr_ln_kernel<<<dim3(128), dim3(256), 0, stream>>>(ddg, zg, indxqg,
                                                         tauvg, vpackg, onrmg,
                                                         gamma, beta, out);
}